// Round 2
// baseline (481.320 us; speedup 1.0000x reference)
//
#include <hip/hip_runtime.h>
#include <math.h>

// DistanceAggregation: B=32 independent sequential boundary scans.
// One wave (64 lanes) per batch; lane owns 8 of the 512 dims (two float4s).
// Per step: shfl_xor butterfly wave-sum of squared diffs -> uniform boundary
// decision -> write mean row (or zeros) + flag; update rep/csum/start_sum.
//
// R1 post-mortem: DPP(row_shr/bcast)+readlane reduction gave run-to-run
// nondeterminism (first launch correct, later launches flipped a boundary).
// Suspected VALU->DPP/readlane wait-state hazard. Replaced with __shfl_xor
// butterfly (ds_swizzle path, hazard-free, sum lands in all lanes).

typedef float v4 __attribute__((ext_vector_type(4)));

#define T_FRAMES 1000
#define D_DIM    512
#define NV4      (D_DIM / 4)   // 128 float4 per frame
#define PF       16            // prefetch depth (steps)

__device__ __forceinline__ v4 sel4(bool c, v4 a, v4 b) {
  v4 r;
  r.x = c ? a.x : b.x;
  r.y = c ? a.y : b.y;
  r.z = c ? a.z : b.z;
  r.w = c ? a.w : b.w;
  return r;
}

// Full 64-lane butterfly sum; every lane ends with the total.
__device__ __forceinline__ float wave_sum64(float x) {
  x += __shfl_xor(x, 1);
  x += __shfl_xor(x, 2);
  x += __shfl_xor(x, 4);
  x += __shfl_xor(x, 8);
  x += __shfl_xor(x, 16);
  x += __shfl_xor(x, 32);
  return x;
}

__global__ __launch_bounds__(64, 1)
void dist_agg_scan(const float* __restrict__ data,
                   const float* __restrict__ thrp,
                   float* __restrict__ out, int B) {
  const int b    = blockIdx.x;
  const int lane = threadIdx.x;
  const float thr = thrp[0];

  const v4* __restrict__ dp = reinterpret_cast<const v4*>(data) + (size_t)b * T_FRAMES * NV4;
  v4* __restrict__ mp       = reinterpret_cast<v4*>(out) + (size_t)b * (T_FRAMES - 1) * NV4;
  float* __restrict__ fp    = out + (size_t)B * (T_FRAMES - 1) * D_DIM + (size_t)b * (T_FRAMES - 1);

  const int s0 = lane;        // float4 slot 0 of this lane
  const int s1 = 64 + lane;   // float4 slot 1

  // carries
  v4 rep0 = dp[s0], rep1 = dp[s1];   // rep = data[0]
  v4 cs0  = rep0,  cs1  = rep1;      // csum = sum(data[:1]) (ready for step i=1)
  v4 ss0  = {0.f, 0.f, 0.f, 0.f};
  v4 ss1  = {0.f, 0.f, 0.f, 0.f};
  int ind = 0, fi = 0;

  // threshold^2 for f=0 (boundary-reset path): a = 0*1-1 = -1
  const float F0     = 1.9f / (1.0f + expf(-1.0f)) + 0.4f;
  const float tf0    = thr * F0;
  const float tf2_f0 = tf0 * tf0;
  float tf2 = tf2_f0;   // entering step 1 with f=0

  // prefetch pipeline: buf[j] holds data[base + j]
  v4 bufa[PF], bufb[PF];
#pragma unroll
  for (int j = 0; j < PF; ++j) {
    bufa[j] = dp[(size_t)(1 + j) * NV4 + s0];
    bufb[j] = dp[(size_t)(1 + j) * NV4 + s1];
  }

  auto step = [&](int i, v4 fa, v4 fb) {
    // speculative next-threshold for the NON-boundary path:
    // factor index would be fi+1 -> a = clip((fi+1)-1, -80, 80) = min(fi, 80)
    float an      = fminf((float)fi, 80.0f);
    float Fn      = 1.9f / (1.0f + expf(an)) + 0.4f;
    float tn      = thr * Fn;
    float tf2_inc = tn * tn;

    // dist^2(rep, frame)
    v4 d0 = rep0 - fa;
    v4 d1 = rep1 - fb;
    float sA = d0.x * d0.x + d0.y * d0.y;
    float sB = d0.z * d0.z + d0.w * d0.w;
    float sC = d1.x * d1.x + d1.y * d1.y;
    float sD = d1.z * d1.z + d1.w * d1.w;
    float part  = (sA + sB) + (sC + sD);
    float dist2 = wave_sum64(part);
    bool  bnd   = dist2 > tf2;

    // segment mean (valid only when bnd; else write zeros)
    float inv = 1.0f / (float)(i - ind);
    v4 df0 = cs0 - ss0;
    v4 df1 = cs1 - ss1;
    v4 m0, m1;
    m0.x = df0.x * inv; m0.y = df0.y * inv; m0.z = df0.z * inv; m0.w = df0.w * inv;
    m1.x = df1.x * inv; m1.y = df1.y * inv; m1.z = df1.z * inv; m1.w = df1.w * inv;
    v4 z = {0.f, 0.f, 0.f, 0.f};
    v4 o0 = sel4(bnd, m0, z);
    v4 o1 = sel4(bnd, m1, z);
    mp[(size_t)(i - 1) * NV4 + s0] = o0;
    mp[(size_t)(i - 1) * NV4 + s1] = o1;
    if (lane == 0) fp[i - 1] = bnd ? 1.0f : 0.0f;

    // carry updates (bnd is wave-uniform: dist2 identical in all lanes)
    rep0 = sel4(bnd, fa, rep0);
    rep1 = sel4(bnd, fb, rep1);
    ss0  = sel4(bnd, cs0, ss0);
    ss1  = sel4(bnd, cs1, ss1);
    ind  = bnd ? i : ind;
    fi   = bnd ? 0 : fi + 1;
    tf2  = bnd ? tf2_f0 : tf2_inc;

    cs0 += fa;
    cs1 += fb;
  };

  int base = 1;
  for (; base + PF <= T_FRAMES; base += PF) {
#pragma unroll
    for (int j = 0; j < PF; ++j) {
      const int i = base + j;
      v4 fa = bufa[j], fb = bufb[j];
      // prefetch frame i+PF into this slot
      if (i + PF < T_FRAMES) {
        bufa[j] = dp[(size_t)(i + PF) * NV4 + s0];
        bufb[j] = dp[(size_t)(i + PF) * NV4 + s1];
      }
      step(i, fa, fb);
    }
  }
  // tail: i in [base, T_FRAMES-1], frames already in buf
#pragma unroll
  for (int j = 0; j < PF; ++j) {
    const int i = base + j;
    if (i < T_FRAMES) {
      step(i, bufa[j], bufb[j]);
    }
  }
}

extern "C" void kernel_launch(void* const* d_in, const int* in_sizes, int n_in,
                              void* d_out, int out_size, void* d_ws, size_t ws_size,
                              hipStream_t stream) {
  const float* data = (const float*)d_in[0];
  const float* thr  = (const float*)d_in[1];
  float* out        = (float*)d_out;
  const int B = in_sizes[0] / (T_FRAMES * D_DIM);
  dist_agg_scan<<<B, 64, 0, stream>>>(data, thr, out, B);
}

// Round 3
// 312.546 us; speedup vs baseline: 1.5400x; 1.5400x over previous
//
#include <hip/hip_runtime.h>
#include <math.h>

// DistanceAggregation, 3-phase decomposition:
//  1) band_kernel: band[b][i][w] = dist^2(f_i, f_{i-1-w}), w<8  (parallel)
//  2) scan_kernel: serial boundary scan, ~scalar ops only; band values via
//     readlane from a register ring prefetched 64 rows ahead; rare exact
//     fallback (full distance recompute) when a segment exceeds 8 frames.
//  3) mean_kernel: segment means / zero rows / flags                (parallel)
// Fallback: monolithic R2 kernel if ws_size too small.

typedef float v4 __attribute__((ext_vector_type(4)));

#define T_F    1000
#define T_PAD  1024          // padded rows for band/scan_out (no upper guards)
#define D_DIM  512
#define NV4    128           // float4 per frame
#define BAND_W 8
#define RUN    27            // rows per wave in band kernel (999 = 27*37)
#define RPB    37            // runs per batch

__device__ __forceinline__ float rl(float v, int l) {
  return __int_as_float(__builtin_amdgcn_readlane(__float_as_int(v), l));
}

__device__ __forceinline__ float wave_sum64(float x) {
  x += __shfl_xor(x, 1);
  x += __shfl_xor(x, 2);
  x += __shfl_xor(x, 4);
  x += __shfl_xor(x, 8);
  x += __shfl_xor(x, 16);
  x += __shfl_xor(x, 32);
  return x;
}

__device__ __forceinline__ v4 sel4(bool c, v4 a, v4 b) {
  v4 r;
  r.x = c ? a.x : b.x; r.y = c ? a.y : b.y;
  r.z = c ? a.z : b.z; r.w = c ? a.w : b.w;
  return r;
}

// ---------------------------------------------------------------- kernel 1
__global__ __launch_bounds__(256)
void band_kernel(const float* __restrict__ data, float* __restrict__ band, int B) {
  const int lane = threadIdx.x & 63;
  const int wid  = threadIdx.x >> 6;
  const int run  = blockIdx.x * 4 + wid;
  if (run >= B * RPB) return;
  const int b  = run / RPB;
  const int k  = run % RPB;
  const int r0 = 1 + k * RUN;            // r0 % 9 == 1 always

  const v4* __restrict__ dp = reinterpret_cast<const v4*>(data) + (size_t)b * T_F * NV4;
  float* __restrict__ bp    = band + (size_t)b * T_PAD * BAND_W;

  const int s0 = lane, s1 = 64 + lane;
  const bool bt0 = (lane & 1) != 0, bt1 = (lane & 2) != 0, bt2 = (lane & 4) != 0;

  // ring: slot (t % 9) holds frame t (8 floats/lane as two v4)
  v4 ra[9], rb[9];
#pragma unroll
  for (int p = 0; p < 9; ++p) { ra[p] = {0.f,0.f,0.f,0.f}; rb[p] = {0.f,0.f,0.f,0.f}; }
#pragma unroll
  for (int d = 1; d <= 8; ++d) {
    const int p = (10 - d) % 9;          // (r0-d) % 9, compile-time
    const int t = r0 - d;
    if (t >= 0) { ra[p] = dp[(size_t)t * NV4 + s0]; rb[p] = dp[(size_t)t * NV4 + s1]; }
  }
  v4 nfa = dp[(size_t)r0 * NV4 + s0];
  v4 nfb = dp[(size_t)r0 * NV4 + s1];

#pragma unroll
  for (int u = 0; u < RUN; ++u) {
    const int i  = r0 + u;
    const int si = (1 + u) % 9;          // slot of frame i
    v4 fa = nfa, fb = nfb;
    // prefetch next frame (clamped; harmless extra load on last row)
    const int tn = (i + 1 < T_F) ? (i + 1) : (T_F - 1);
    nfa = dp[(size_t)tn * NV4 + s0];
    nfb = dp[(size_t)tn * NV4 + s1];
    ra[si] = fa; rb[si] = fb;

    float p[8];
#pragma unroll
    for (int w = 0; w < 8; ++w) {
      const int sj = (u - w + 9) % 9;    // slot of frame i-1-w, compile-time
      v4 d0 = fa - ra[sj];
      v4 d1 = fb - rb[sj];
      p[w] = d0.x*d0.x + d0.y*d0.y + d0.z*d0.z + d0.w*d0.w
           + d1.x*d1.x + d1.y*d1.y + d1.z*d1.z + d1.w*d1.w;
    }
    // 3 butterfly levels per w (group-of-8 sums) ...
#pragma unroll
    for (int w = 0; w < 8; ++w) {
      p[w] += __shfl_xor(p[w], 1);
      p[w] += __shfl_xor(p[w], 2);
      p[w] += __shfl_xor(p[w], 4);
    }
    // ... select p[lane&7] per lane (7 cndmask) ...
    float q0 = bt0 ? p[1] : p[0];
    float q1 = bt0 ? p[3] : p[2];
    float q2 = bt0 ? p[5] : p[4];
    float q3 = bt0 ? p[7] : p[6];
    float h0 = bt1 ? q1 : q0;
    float h1 = bt1 ? q3 : q2;
    float comb = bt2 ? h1 : h0;
    // ... and 3 cross-group levels: lane L = total for w = L&7
    comb += __shfl_xor(comb, 8);
    comb += __shfl_xor(comb, 16);
    comb += __shfl_xor(comb, 32);
    if (lane < 8) {
      float val = (i - 1 - lane >= 0) ? comb : 1e30f;
      bp[(size_t)i * BAND_W + lane] = val;
    }
  }
}

// ---------------------------------------------------------------- kernel 2
__device__ __attribute__((noinline))
float slow_d2(const v4* __restrict__ dp, int j, int i, int lane) {
  v4 a0 = dp[(size_t)j * NV4 + lane];
  v4 a1 = dp[(size_t)j * NV4 + 64 + lane];
  v4 b0 = dp[(size_t)i * NV4 + lane];
  v4 b1 = dp[(size_t)i * NV4 + 64 + lane];
  v4 d0 = a0 - b0, d1 = a1 - b1;
  float s = d0.x*d0.x + d0.y*d0.y + d0.z*d0.z + d0.w*d0.w
          + d1.x*d1.x + d1.y*d1.y + d1.z*d1.z + d1.w*d1.w;
  return wave_sum64(s);
}

__global__ __launch_bounds__(64, 1)
void scan_kernel(const float* __restrict__ data, const float* __restrict__ thrp,
                 const float* __restrict__ band, int* __restrict__ scan_out, int B) {
  const int b    = blockIdx.x;
  const int lane = threadIdx.x;
  const float thr = thrp[0];
  const float* __restrict__ bp = band + (size_t)b * T_PAD * BAND_W;
  const v4* __restrict__ dp    = reinterpret_cast<const v4*>(data) + (size_t)b * T_F * NV4;
  int* __restrict__ so         = scan_out + (size_t)b * T_PAD;

  // tf2 table in lane l: (thr * F[l])^2, F[x] = 1.9/(1+exp(clip(x-1,-80,80)))+0.4
  // (F saturates to fp32 0.4 by x~20, so clamping the index at 63 is exact)
  float aa = fminf(fmaxf((float)lane - 1.0f, -80.0f), 80.0f);
  float Ff = 1.9f / (1.0f + expf(aa)) + 0.4f;
  float tt = thr * Ff;
  const float tf2tab = tt * tt;
  const float tf2_0  = rl(tf2tab, 0);

  // ring: vr[c] covers 8 band rows (64 floats); lane = row_in_chunk*8 + w
  float vr[8];
#pragma unroll
  for (int c = 0; c < 8; ++c) vr[c] = bp[c * 64 + lane];   // rows 0..63

  int ind = 0, fi = 0;
  float tf2 = tf2_0;

  for (int mm = 0; mm < T_PAD / 64; ++mm) {
#pragma unroll
    for (int cc = 0; cc < 8; ++cc) {
#pragma unroll
      for (int u = 0; u < 8; ++u) {
        const int i = mm * 64 + cc * 8 + u;
        if (i > 0) {   // folds to true except the single (0,0,0) slot
          float tnb = rl(tf2tab, min(fi + 1, 63));   // speculative next tf2
          int w = i - 1 - ind;
          float d2;
          if (w < BAND_W) {
            d2 = rl(vr[cc], u * 8 + w);
          } else if (i <= T_F - 1) {
            d2 = slow_d2(dp, ind, i, lane);          // rare exact fallback
          } else {
            d2 = 0.0f;                               // padded rows: don't care
          }
          bool bnd = d2 > tf2;
          if (lane == 0) so[i] = bnd ? ind : -1;
          ind = bnd ? i : ind;
          fi  = bnd ? 0 : fi + 1;
          tf2 = bnd ? tf2_0 : tnb;
        }
      }
      const int nb = (mm + 1) * 64 + cc * 8;         // refill 64 rows ahead
      if (nb <= T_PAD - 8) vr[cc] = bp[nb * 8 + lane];
    }
  }
}

// ---------------------------------------------------------------- kernel 3
__global__ __launch_bounds__(256)
void mean_kernel(const float* __restrict__ data, const int* __restrict__ scan_out,
                 float* __restrict__ out, int B) {
  const int lane = threadIdx.x & 63;
  const int wid  = threadIdx.x >> 6;
  const int b    = blockIdx.y;
  const v4* __restrict__ dp  = reinterpret_cast<const v4*>(data) + (size_t)b * T_F * NV4;
  const int* __restrict__ so = scan_out + (size_t)b * T_PAD;
  v4* __restrict__ mp        = reinterpret_cast<v4*>(out) + (size_t)b * (T_F - 1) * NV4;
  float* __restrict__ fl     = out + (size_t)B * (T_F - 1) * D_DIM + (size_t)b * (T_F - 1);
  const int s0 = lane, s1 = 64 + lane;

#pragma unroll
  for (int q = 0; q < 4; ++q) {
    const int i = 1 + blockIdx.x * 16 + wid * 4 + q;
    if (i <= T_F - 1) {
      const int s = so[i];
      v4 acc0 = {0.f,0.f,0.f,0.f}, acc1 = {0.f,0.f,0.f,0.f};
      float flag = 0.0f;
      if (s >= 0) {
        for (int t = s; t < i; ++t) {
          acc0 += dp[(size_t)t * NV4 + s0];
          acc1 += dp[(size_t)t * NV4 + s1];
        }
        const float invl = 1.0f / (float)(i - s);
        acc0.x *= invl; acc0.y *= invl; acc0.z *= invl; acc0.w *= invl;
        acc1.x *= invl; acc1.y *= invl; acc1.z *= invl; acc1.w *= invl;
        flag = 1.0f;
      }
      mp[(size_t)(i - 1) * NV4 + s0] = acc0;
      mp[(size_t)(i - 1) * NV4 + s1] = acc1;
      if (lane == 0) fl[i - 1] = flag;
    }
  }
}

// --------------------------------------------------- fallback (R2, green)
__global__ __launch_bounds__(64, 1)
void dist_agg_mono(const float* __restrict__ data,
                   const float* __restrict__ thrp,
                   float* __restrict__ out, int B) {
  const int b    = blockIdx.x;
  const int lane = threadIdx.x;
  const float thr = thrp[0];
  const v4* __restrict__ dp = reinterpret_cast<const v4*>(data) + (size_t)b * T_F * NV4;
  v4* __restrict__ mp       = reinterpret_cast<v4*>(out) + (size_t)b * (T_F - 1) * NV4;
  float* __restrict__ fp    = out + (size_t)B * (T_F - 1) * D_DIM + (size_t)b * (T_F - 1);
  const int s0 = lane, s1 = 64 + lane;

  v4 rep0 = dp[s0], rep1 = dp[s1];
  v4 cs0  = rep0,  cs1  = rep1;
  v4 ss0  = {0.f,0.f,0.f,0.f}, ss1 = {0.f,0.f,0.f,0.f};
  int ind = 0, fi = 0;
  const float F0     = 1.9f / (1.0f + expf(-1.0f)) + 0.4f;
  const float tf0    = thr * F0;
  const float tf2_f0 = tf0 * tf0;
  float tf2 = tf2_f0;

  for (int i = 1; i < T_F; ++i) {
    float an      = fminf((float)fi, 80.0f);
    float Fn      = 1.9f / (1.0f + expf(an)) + 0.4f;
    float tn      = thr * Fn;
    float tf2_inc = tn * tn;
    v4 fa = dp[(size_t)i * NV4 + s0];
    v4 fb = dp[(size_t)i * NV4 + s1];
    v4 d0 = rep0 - fa, d1 = rep1 - fb;
    float part = d0.x*d0.x + d0.y*d0.y + d0.z*d0.z + d0.w*d0.w
               + d1.x*d1.x + d1.y*d1.y + d1.z*d1.z + d1.w*d1.w;
    float dist2 = wave_sum64(part);
    bool bnd = dist2 > tf2;
    float inv = 1.0f / (float)(i - ind);
    v4 df0 = cs0 - ss0, df1 = cs1 - ss1;
    v4 m0, m1, z = {0.f,0.f,0.f,0.f};
    m0.x = df0.x*inv; m0.y = df0.y*inv; m0.z = df0.z*inv; m0.w = df0.w*inv;
    m1.x = df1.x*inv; m1.y = df1.y*inv; m1.z = df1.z*inv; m1.w = df1.w*inv;
    mp[(size_t)(i-1) * NV4 + s0] = sel4(bnd, m0, z);
    mp[(size_t)(i-1) * NV4 + s1] = sel4(bnd, m1, z);
    if (lane == 0) fp[i-1] = bnd ? 1.0f : 0.0f;
    rep0 = sel4(bnd, fa, rep0); rep1 = sel4(bnd, fb, rep1);
    ss0  = sel4(bnd, cs0, ss0); ss1  = sel4(bnd, cs1, ss1);
    ind  = bnd ? i : ind;
    fi   = bnd ? 0 : fi + 1;
    tf2  = bnd ? tf2_f0 : tf2_inc;
    cs0 += fa; cs1 += fb;
  }
}

// ----------------------------------------------------------------- launch
extern "C" void kernel_launch(void* const* d_in, const int* in_sizes, int n_in,
                              void* d_out, int out_size, void* d_ws, size_t ws_size,
                              hipStream_t stream) {
  const float* data = (const float*)d_in[0];
  const float* thr  = (const float*)d_in[1];
  float* out        = (float*)d_out;
  const int B = in_sizes[0] / (T_F * D_DIM);

  const size_t band_elems = (size_t)B * T_PAD * BAND_W;
  const size_t need = band_elems * 4 + (size_t)B * T_PAD * 4;

  if (ws_size >= need) {
    float* band   = (float*)d_ws;
    int* scan_out = (int*)((float*)d_ws + band_elems);
    const int runs = B * RPB;
    band_kernel<<<(runs + 3) / 4, 256, 0, stream>>>(data, band, B);
    scan_kernel<<<B, 64, 0, stream>>>(data, thr, band, scan_out, B);
    mean_kernel<<<dim3((T_F - 2) / 16 + 1, B), 256, 0, stream>>>(data, scan_out, out, B);
  } else {
    dist_agg_mono<<<B, 64, 0, stream>>>(data, thr, out, B);
  }
}

// Round 4
// 160.072 us; speedup vs baseline: 3.0069x; 1.9525x over previous
//
#include <hip/hip_runtime.h>
#include <math.h>

// DistanceAggregation v4.
// Identity: f_i == i-1-ind  =>  boundary test at step i with last boundary s is
//   dist^2(f_s, f_i) > (thr*F[i-1-s])^2   -- no carried threshold state.
// 1) band_kernel: per segment-start s, delta[s] = 1+first w<8 that is a
//    boundary (0 = none within 8 = overflow sentinel).       [parallel]
// 2) scan_kernel: chase delta[] (nibble-packed in 2 VGPRs/lane, readlane
//    hops ~1/segment); mark so[i]=s at boundaries; exact cold fallback.
// 3) mean_kernel: branch-free 8-wide clamped-load segment means. [parallel]

typedef float v4 __attribute__((ext_vector_type(4)));

#define T_F    1000
#define D_DIM  512
#define NV4    128
#define RUN2   9            // rows per wave in band kernel (999 = 9*111)
#define RPB2   111

__device__ __forceinline__ float wave_sum64(float x) {
  x += __shfl_xor(x, 1);
  x += __shfl_xor(x, 2);
  x += __shfl_xor(x, 4);
  x += __shfl_xor(x, 8);
  x += __shfl_xor(x, 16);
  x += __shfl_xor(x, 32);
  return x;
}

__device__ __forceinline__ v4 sel4(bool c, v4 a, v4 b) {
  v4 r;
  r.x = c ? a.x : b.x; r.y = c ? a.y : b.y;
  r.z = c ? a.z : b.z; r.w = c ? a.w : b.w;
  return r;
}

// 8 bytes (two u32, values 0..15) -> 8 packed nibbles
__device__ __forceinline__ unsigned pack8(unsigned x, unsigned y) {
  unsigned a = x & 0x0F0F0F0Fu; a |= a >> 4;
  unsigned p = (a & 0xFFu) | ((a >> 8) & 0xFF00u);
  unsigned b = y & 0x0F0F0F0Fu; b |= b >> 4;
  unsigned q = (b & 0xFFu) | ((b >> 8) & 0xFF00u);
  return p | (q << 16);
}

// ---------------------------------------------------------------- kernel 1
__global__ __launch_bounds__(256)
void band_kernel(const float* __restrict__ data, const float* __restrict__ thrp,
                 unsigned char* __restrict__ deltab, int B) {
  const int lane = threadIdx.x & 63;
  const int wid  = threadIdx.x >> 6;
  const int run  = blockIdx.x * 4 + wid;
  if (run >= B * RPB2) return;
  const int b   = run / RPB2;
  const int s0i = (run % RPB2) * RUN2;       // s0i % 9 == 0

  const v4* __restrict__ dp = reinterpret_cast<const v4*>(data) + (size_t)b * T_F * NV4;
  unsigned char* __restrict__ dbp = deltab + (size_t)b * 1024;

  // per-lane threshold^2 for w = lane&7:  F[w] = 1.9/(1+exp(w-1))+0.4
  const int   wl  = lane & 7;
  const float thr = thrp[0];
  float Ff  = 1.9f / (1.0f + expf((float)wl - 1.0f)) + 0.4f;
  float tt  = thr * Ff;
  const float tf2l = tt * tt;

  const int q0 = lane, q1 = 64 + lane;
  // ring: slot t%9 holds frame t; init t = s0i..s0i+8 -> slot d = t - s0i
  v4 ra[9], rb[9];
#pragma unroll
  for (int d = 0; d < 9; ++d) {
    int t = s0i + d; if (t > T_F - 1) t = T_F - 1;
    ra[d] = dp[(size_t)t * NV4 + q0];
    rb[d] = dp[(size_t)t * NV4 + q1];
  }

#pragma unroll
  for (int u = 0; u < RUN2; ++u) {
    const int s = s0i + u;                   // segment start
    float p[8];
#pragma unroll
    for (int w = 0; w < 8; ++w) {
      const int sj = (u + 1 + w) % 9;        // slot of frame s+1+w (compile-time)
      v4 d0 = ra[u] - ra[sj];
      v4 d1 = rb[u] - rb[sj];
      p[w] = d0.x*d0.x + d0.y*d0.y + d0.z*d0.z + d0.w*d0.w
           + d1.x*d1.x + d1.y*d1.y + d1.z*d1.z + d1.w*d1.w;
    }
#pragma unroll
    for (int w = 0; w < 8; ++w) {
      p[w] += __shfl_xor(p[w], 1);
      p[w] += __shfl_xor(p[w], 2);
      p[w] += __shfl_xor(p[w], 4);
    }
    const bool bt0 = (lane & 1) != 0, bt1 = (lane & 2) != 0, bt2 = (lane & 4) != 0;
    float q0v = bt0 ? p[1] : p[0];
    float q1v = bt0 ? p[3] : p[2];
    float q2v = bt0 ? p[5] : p[4];
    float q3v = bt0 ? p[7] : p[6];
    float h0  = bt1 ? q1v : q0v;
    float h1  = bt1 ? q3v : q2v;
    float comb = bt2 ? h1 : h0;
    comb += __shfl_xor(comb, 8);
    comb += __shfl_xor(comb, 16);
    comb += __shfl_xor(comb, 32);
    // lane L now holds full dist^2 for w=L&7
    bool valid = (s + 1 + wl) <= (T_F - 1);
    bool bnd   = valid && (comb > tf2l);
    unsigned long long m = __ballot(bnd);
    int delta = __ffsll((unsigned long long)(m & 0xFFull));  // 1..8, 0 = none
    if (lane == 0) dbp[s] = (unsigned char)delta;
    // slide ring: slot u <- frame s+9 (needed next row as w=7)
    if (u + 1 < RUN2) {
      int tn = s + 9; if (tn > T_F - 1) tn = T_F - 1;
      ra[u] = dp[(size_t)tn * NV4 + q0];
      rb[u] = dp[(size_t)tn * NV4 + q1];
    }
  }
}

// ---------------------------------------------------------------- kernel 2
__global__ __launch_bounds__(64, 1)
void scan_kernel(const float* __restrict__ data, const float* __restrict__ thrp,
                 const unsigned char* __restrict__ deltab,
                 int* __restrict__ scan_out, int B) {
  const int b    = blockIdx.x;
  const int lane = threadIdx.x;
  const v4* __restrict__ dp = reinterpret_cast<const v4*>(data) + (size_t)b * T_F * NV4;
  int* __restrict__ so = scan_out + (size_t)b * 1024;

  // default: no boundary
#pragma unroll
  for (int j = 0; j < 16; ++j) so[j * 64 + lane] = -1;

  // pack 16 delta bytes per lane into 2 nibble words
  const uint4 dd = reinterpret_cast<const uint4*>(deltab + (size_t)b * 1024)[lane];
  unsigned plo = pack8(dd.x, dd.y);
  unsigned phi = pack8(dd.z, dd.w);

  __builtin_amdgcn_s_waitcnt(0);   // -1 stores drained before chase overwrites

  int s = 0;
  bool need_exact = false;
  while (s < T_F - 1) {
    unsigned lo = (unsigned)__builtin_amdgcn_readlane((int)plo, s >> 4);
    unsigned hi = (unsigned)__builtin_amdgcn_readlane((int)phi, s >> 4);
    unsigned word = (s & 8) ? hi : lo;
    int delta = (word >> ((s & 7) * 4)) & 15;
    if (delta == 0) { need_exact = (s < T_F - 1 - 8); break; }
    s += delta;
    if (lane == 0) so[s] = s - delta;
  }

  if (need_exact) {   // cold: exact continuation from last boundary s
    const float thr = thrp[0];
    const int q0 = lane, q1 = 64 + lane;
    int ind = s, f = 0;
    v4 rep0 = dp[(size_t)ind * NV4 + q0];
    v4 rep1 = dp[(size_t)ind * NV4 + q1];
    for (int i = s + 1; i <= T_F - 1; ++i) {
      float av = fminf((float)f - 1.0f, 80.0f);
      float Ff = 1.9f / (1.0f + expf(av)) + 0.4f;
      float t2 = thr * Ff; t2 *= t2;
      v4 x0 = dp[(size_t)i * NV4 + q0];
      v4 x1 = dp[(size_t)i * NV4 + q1];
      v4 d0 = rep0 - x0, d1 = rep1 - x1;
      float part = d0.x*d0.x + d0.y*d0.y + d0.z*d0.z + d0.w*d0.w
                 + d1.x*d1.x + d1.y*d1.y + d1.z*d1.z + d1.w*d1.w;
      float d2 = wave_sum64(part);
      bool bnd = d2 > t2;
      if (bnd) {
        if (lane == 0) so[i] = ind;
        ind = i; f = 0; rep0 = x0; rep1 = x1;
      } else {
        f += 1;
      }
    }
  }
}

// ---------------------------------------------------------------- kernel 3
__global__ __launch_bounds__(256)
void mean_kernel(const float* __restrict__ data, const int* __restrict__ scan_out,
                 float* __restrict__ out, int B) {
  const int lane = threadIdx.x & 63;
  const int wid  = threadIdx.x >> 6;
  const int b    = blockIdx.y;
  const int i    = 1 + blockIdx.x * 4 + wid;
  if (i > T_F - 1) return;

  const v4* __restrict__ dp  = reinterpret_cast<const v4*>(data) + (size_t)b * T_F * NV4;
  const int* __restrict__ so = scan_out + (size_t)b * 1024;
  v4* __restrict__ mp        = reinterpret_cast<v4*>(out) + (size_t)b * (T_F - 1) * NV4;
  float* __restrict__ fl     = out + (size_t)B * (T_F - 1) * D_DIM + (size_t)b * (T_F - 1);
  const int q0 = lane, q1 = 64 + lane;

  const int s = so[i];
  v4 z = {0.f, 0.f, 0.f, 0.f};
  if (s < 0) {
    mp[(size_t)(i - 1) * NV4 + q0] = z;
    mp[(size_t)(i - 1) * NV4 + q1] = z;
    if (lane == 0) fl[i - 1] = 0.0f;
    return;
  }
  const int len = i - s;
  v4 a0 = z, a1 = z;
#pragma unroll
  for (int j = 0; j < 8; ++j) {
    bool val = j < len;
    int t = val ? s + j : s;               // clamped, always in-bounds
    v4 x0 = dp[(size_t)t * NV4 + q0];
    v4 x1 = dp[(size_t)t * NV4 + q1];
    float msk = val ? 1.0f : 0.0f;
    a0.x += x0.x * msk; a0.y += x0.y * msk; a0.z += x0.z * msk; a0.w += x0.w * msk;
    a1.x += x1.x * msk; a1.y += x1.y * msk; a1.z += x1.z * msk; a1.w += x1.w * msk;
  }
  if (len > 8) {                           // cold (only after exact fallback)
    for (int t = s + 8; t < i; ++t) {
      a0 += dp[(size_t)t * NV4 + q0];
      a1 += dp[(size_t)t * NV4 + q1];
    }
  }
  const float inv = 1.0f / (float)len;
  a0.x *= inv; a0.y *= inv; a0.z *= inv; a0.w *= inv;
  a1.x *= inv; a1.y *= inv; a1.z *= inv; a1.w *= inv;
  mp[(size_t)(i - 1) * NV4 + q0] = a0;
  mp[(size_t)(i - 1) * NV4 + q1] = a1;
  if (lane == 0) fl[i - 1] = 1.0f;
}

// --------------------------------------------------- fallback (R2, green)
__global__ __launch_bounds__(64, 1)
void dist_agg_mono(const float* __restrict__ data,
                   const float* __restrict__ thrp,
                   float* __restrict__ out, int B) {
  const int b    = blockIdx.x;
  const int lane = threadIdx.x;
  const float thr = thrp[0];
  const v4* __restrict__ dp = reinterpret_cast<const v4*>(data) + (size_t)b * T_F * NV4;
  v4* __restrict__ mp       = reinterpret_cast<v4*>(out) + (size_t)b * (T_F - 1) * NV4;
  float* __restrict__ fp    = out + (size_t)B * (T_F - 1) * D_DIM + (size_t)b * (T_F - 1);
  const int s0 = lane, s1 = 64 + lane;

  v4 rep0 = dp[s0], rep1 = dp[s1];
  v4 cs0  = rep0,  cs1  = rep1;
  v4 ss0  = {0.f,0.f,0.f,0.f}, ss1 = {0.f,0.f,0.f,0.f};
  int ind = 0, fi = 0;
  const float F0     = 1.9f / (1.0f + expf(-1.0f)) + 0.4f;
  const float tf0    = thr * F0;
  const float tf2_f0 = tf0 * tf0;
  float tf2 = tf2_f0;

  for (int i = 1; i < T_F; ++i) {
    float an      = fminf((float)fi, 80.0f);
    float Fn      = 1.9f / (1.0f + expf(an)) + 0.4f;
    float tn      = thr * Fn;
    float tf2_inc = tn * tn;
    v4 fa = dp[(size_t)i * NV4 + s0];
    v4 fb = dp[(size_t)i * NV4 + s1];
    v4 d0 = rep0 - fa, d1 = rep1 - fb;
    float part = d0.x*d0.x + d0.y*d0.y + d0.z*d0.z + d0.w*d0.w
               + d1.x*d1.x + d1.y*d1.y + d1.z*d1.z + d1.w*d1.w;
    float dist2 = wave_sum64(part);
    bool bnd = dist2 > tf2;
    float inv = 1.0f / (float)(i - ind);
    v4 df0 = cs0 - ss0, df1 = cs1 - ss1;
    v4 m0, m1, z = {0.f,0.f,0.f,0.f};
    m0.x = df0.x*inv; m0.y = df0.y*inv; m0.z = df0.z*inv; m0.w = df0.w*inv;
    m1.x = df1.x*inv; m1.y = df1.y*inv; m1.z = df1.z*inv; m1.w = df1.w*inv;
    mp[(size_t)(i-1) * NV4 + s0] = sel4(bnd, m0, z);
    mp[(size_t)(i-1) * NV4 + s1] = sel4(bnd, m1, z);
    if (lane == 0) fp[i-1] = bnd ? 1.0f : 0.0f;
    rep0 = sel4(bnd, fa, rep0); rep1 = sel4(bnd, fb, rep1);
    ss0  = sel4(bnd, cs0, ss0); ss1  = sel4(bnd, cs1, ss1);
    ind  = bnd ? i : ind;
    fi   = bnd ? 0 : fi + 1;
    tf2  = bnd ? tf2_f0 : tf2_inc;
    cs0 += fa; cs1 += fb;
  }
}

// ----------------------------------------------------------------- launch
extern "C" void kernel_launch(void* const* d_in, const int* in_sizes, int n_in,
                              void* d_out, int out_size, void* d_ws, size_t ws_size,
                              hipStream_t stream) {
  const float* data = (const float*)d_in[0];
  const float* thr  = (const float*)d_in[1];
  float* out        = (float*)d_out;
  const int B = in_sizes[0] / (T_F * D_DIM);

  const size_t need = (size_t)B * 1024 + (size_t)B * 1024 * 4;  // delta + so

  if (ws_size >= need) {
    unsigned char* deltab = (unsigned char*)d_ws;
    int* scan_out = (int*)((unsigned char*)d_ws + (size_t)B * 1024);
    const int runs = B * RPB2;
    band_kernel<<<(runs + 3) / 4, 256, 0, stream>>>(data, thr, deltab, B);
    scan_kernel<<<B, 64, 0, stream>>>(data, thr, deltab, scan_out, B);
    mean_kernel<<<dim3((T_F - 2) / 4 + 1, B), 256, 0, stream>>>(data, scan_out, out, B);
  } else {
    dist_agg_mono<<<B, 64, 0, stream>>>(data, thr, out, B);
  }
}

// Round 5
// 154.241 us; speedup vs baseline: 3.1206x; 1.0378x over previous
//
#include <hip/hip_runtime.h>
#include <math.h>

// DistanceAggregation v5.
// Identity: f_i == i-1-ind  =>  boundary test at step i with last boundary s is
//   dist^2(f_s, f_i) > (thr*F[i-1-s])^2   -- no carried threshold state.
// 1) band_kernel (W=4): per segment-start s, delta[s] = 1+first w<4 that is a
//    boundary (0 = none within 4 = overflow sentinel).        [parallel]
//    W=4 justified statistically (w=2 fires at +4.4 sigma, w=3 at +11 sigma for
//    N(0,1) data, thr=30); sentinel->exact fallback keeps ANY data correct.
// 2) scan_kernel: chase delta[] (nibble-packed, 2 VGPRs/lane, ~1 readlane
//    hop per segment); so[i]=segment start at boundaries; exact cold fallback.
// 3) mean_kernel: branch-free 4-wide clamped-load segment means.  [parallel]
// Note: measured dur includes ~82us of harness d_ws/d_out poison fills.

typedef float v4 __attribute__((ext_vector_type(4)));

#define T_F    1000
#define D_DIM  512
#define NV4    128
#define BAND_W 4
#define RUNB   9            // rows per wave in band kernel (999 = 9*111)
#define RPBB   111

__device__ __forceinline__ float wave_sum64(float x) {
  x += __shfl_xor(x, 1);
  x += __shfl_xor(x, 2);
  x += __shfl_xor(x, 4);
  x += __shfl_xor(x, 8);
  x += __shfl_xor(x, 16);
  x += __shfl_xor(x, 32);
  return x;
}

__device__ __forceinline__ v4 sel4(bool c, v4 a, v4 b) {
  v4 r;
  r.x = c ? a.x : b.x; r.y = c ? a.y : b.y;
  r.z = c ? a.z : b.z; r.w = c ? a.w : b.w;
  return r;
}

// 8 bytes (two u32, values 0..15) -> 8 packed nibbles
__device__ __forceinline__ unsigned pack8(unsigned x, unsigned y) {
  unsigned a = x & 0x0F0F0F0Fu; a |= a >> 4;
  unsigned p = (a & 0xFFu) | ((a >> 8) & 0xFF00u);
  unsigned b = y & 0x0F0F0F0Fu; b |= b >> 4;
  unsigned q = (b & 0xFFu) | ((b >> 8) & 0xFF00u);
  return p | (q << 16);
}

// ---------------------------------------------------------------- kernel 1
__global__ __launch_bounds__(256)
void band_kernel(const float* __restrict__ data, const float* __restrict__ thrp,
                 unsigned char* __restrict__ deltab, int B) {
  const int lane = threadIdx.x & 63;
  const int wid  = threadIdx.x >> 6;
  const int run  = blockIdx.x * 4 + wid;
  if (run >= B * RPBB) return;
  const int b   = run / RPBB;
  const int s0i = (run % RPBB) * RUNB;       // s0i % 9 == 0

  const v4* __restrict__ dp = reinterpret_cast<const v4*>(data) + (size_t)b * T_F * NV4;
  unsigned char* __restrict__ dbp = deltab + (size_t)b * 1024;

  // per-lane threshold^2 for w = lane&3:  F[w] = 1.9/(1+exp(w-1))+0.4
  const int   wl  = lane & 3;
  const float thr = thrp[0];
  float Ff  = 1.9f / (1.0f + expf((float)wl - 1.0f)) + 0.4f;
  float tt  = thr * Ff;
  const float tf2l = tt * tt;

  const int q0 = lane, q1 = 64 + lane;
  // ring: slot t%9 holds frame t; init frames s0i..s0i+8 (clamped)
  v4 ra[9], rb[9];
#pragma unroll
  for (int d = 0; d < 9; ++d) {
    int t = s0i + d; if (t > T_F - 1) t = T_F - 1;
    ra[d] = dp[(size_t)t * NV4 + q0];
    rb[d] = dp[(size_t)t * NV4 + q1];
  }

#pragma unroll
  for (int u = 0; u < RUNB; ++u) {
    const int s = s0i + u;                   // segment start
    float p[BAND_W];
#pragma unroll
    for (int w = 0; w < BAND_W; ++w) {
      const int sj = (u + 1 + w) % 9;        // slot of frame s+1+w (compile-time)
      v4 d0 = ra[u] - ra[sj];
      v4 d1 = rb[u] - rb[sj];
      p[w] = d0.x*d0.x + d0.y*d0.y + d0.z*d0.z + d0.w*d0.w
           + d1.x*d1.x + d1.y*d1.y + d1.z*d1.z + d1.w*d1.w;
    }
#pragma unroll
    for (int w = 0; w < BAND_W; ++w) {
      p[w] += __shfl_xor(p[w], 1);
      p[w] += __shfl_xor(p[w], 2);
      p[w] += __shfl_xor(p[w], 4);
    }
    const bool bt0 = (lane & 1) != 0, bt1 = (lane & 2) != 0;
    float q0v  = bt0 ? p[1] : p[0];
    float q1v  = bt0 ? p[3] : p[2];
    float comb = bt1 ? q1v : q0v;
    comb += __shfl_xor(comb, 8);
    comb += __shfl_xor(comb, 16);
    comb += __shfl_xor(comb, 32);
    // lane L now holds full dist^2 for w = L&3
    bool valid = (s + 1 + wl) <= (T_F - 1);
    bool bnd   = valid && (comb > tf2l);
    unsigned long long m = __ballot(bnd);
    int delta = __ffsll((unsigned long long)(m & 0xFull));  // 1..4, 0 = none
    if (lane == 0) dbp[s] = (unsigned char)delta;
    // slide: frames s0i+9..s0i+12 (slot u), needed from row u+5 onward
    if (u < 4) {
      int tn = s0i + 9 + u; if (tn > T_F - 1) tn = T_F - 1;
      ra[u] = dp[(size_t)tn * NV4 + q0];
      rb[u] = dp[(size_t)tn * NV4 + q1];
    }
  }
}

// ---------------------------------------------------------------- kernel 2
__global__ __launch_bounds__(64, 1)
void scan_kernel(const float* __restrict__ data, const float* __restrict__ thrp,
                 const unsigned char* __restrict__ deltab,
                 int* __restrict__ scan_out, int B) {
  const int b    = blockIdx.x;
  const int lane = threadIdx.x;
  const v4* __restrict__ dp = reinterpret_cast<const v4*>(data) + (size_t)b * T_F * NV4;
  int* __restrict__ so = scan_out + (size_t)b * 1024;

  // default: no boundary
#pragma unroll
  for (int j = 0; j < 16; ++j) so[j * 64 + lane] = -1;

  // pack 16 delta bytes per lane into 2 nibble words
  const uint4 dd = reinterpret_cast<const uint4*>(deltab + (size_t)b * 1024)[lane];
  unsigned plo = pack8(dd.x, dd.y);
  unsigned phi = pack8(dd.z, dd.w);

  __builtin_amdgcn_s_waitcnt(0);   // -1 stores drained before chase overwrites

  int s = 0;
  bool need_exact = false;
  while (s < T_F - 1) {
    unsigned lo = (unsigned)__builtin_amdgcn_readlane((int)plo, s >> 4);
    unsigned hi = (unsigned)__builtin_amdgcn_readlane((int)phi, s >> 4);
    unsigned word = (s & 8) ? hi : lo;
    int delta = (word >> ((s & 7) * 4)) & 15;
    if (delta == 0) { need_exact = (s < T_F - 1 - BAND_W); break; }
    s += delta;
    if (lane == 0) so[s] = s - delta;
  }

  if (need_exact) {   // cold: exact continuation from last boundary s
    const float thr = thrp[0];
    const int q0 = lane, q1 = 64 + lane;
    int ind = s, f = 0;
    v4 rep0 = dp[(size_t)ind * NV4 + q0];
    v4 rep1 = dp[(size_t)ind * NV4 + q1];
    for (int i = s + 1; i <= T_F - 1; ++i) {
      float av = fminf((float)f - 1.0f, 80.0f);
      float Ff = 1.9f / (1.0f + expf(av)) + 0.4f;
      float t2 = thr * Ff; t2 *= t2;
      v4 x0 = dp[(size_t)i * NV4 + q0];
      v4 x1 = dp[(size_t)i * NV4 + q1];
      v4 d0 = rep0 - x0, d1 = rep1 - x1;
      float part = d0.x*d0.x + d0.y*d0.y + d0.z*d0.z + d0.w*d0.w
                 + d1.x*d1.x + d1.y*d1.y + d1.z*d1.z + d1.w*d1.w;
      float d2 = wave_sum64(part);
      bool bnd = d2 > t2;
      if (bnd) {
        if (lane == 0) so[i] = ind;
        ind = i; f = 0; rep0 = x0; rep1 = x1;
      } else {
        f += 1;
      }
    }
  }
}

// ---------------------------------------------------------------- kernel 3
__global__ __launch_bounds__(256)
void mean_kernel(const float* __restrict__ data, const int* __restrict__ scan_out,
                 float* __restrict__ out, int B) {
  const int lane = threadIdx.x & 63;
  const int wid  = threadIdx.x >> 6;
  const int b    = blockIdx.y;
  const v4* __restrict__ dp  = reinterpret_cast<const v4*>(data) + (size_t)b * T_F * NV4;
  const int* __restrict__ so = scan_out + (size_t)b * 1024;
  v4* __restrict__ mp        = reinterpret_cast<v4*>(out) + (size_t)b * (T_F - 1) * NV4;
  float* __restrict__ fl     = out + (size_t)B * (T_F - 1) * D_DIM + (size_t)b * (T_F - 1);
  const int q0 = lane, q1 = 64 + lane;

#pragma unroll
  for (int q = 0; q < 2; ++q) {           // 2 independent rows per wave (ILP)
    const int i = 1 + blockIdx.x * 8 + wid * 2 + q;
    if (i > T_F - 1) continue;
    const int s = so[i];
    v4 z = {0.f, 0.f, 0.f, 0.f};
    if (s < 0) {
      mp[(size_t)(i - 1) * NV4 + q0] = z;
      mp[(size_t)(i - 1) * NV4 + q1] = z;
      if (lane == 0) fl[i - 1] = 0.0f;
      continue;
    }
    const int len = i - s;
    v4 a0 = z, a1 = z;
#pragma unroll
    for (int j = 0; j < BAND_W; ++j) {     // hot: len <= 4
      bool val = j < len;
      int t = val ? s + j : s;             // clamped, always in-bounds
      v4 x0 = dp[(size_t)t * NV4 + q0];
      v4 x1 = dp[(size_t)t * NV4 + q1];
      float msk = val ? 1.0f : 0.0f;
      a0.x += x0.x * msk; a0.y += x0.y * msk; a0.z += x0.z * msk; a0.w += x0.w * msk;
      a1.x += x1.x * msk; a1.y += x1.y * msk; a1.z += x1.z * msk; a1.w += x1.w * msk;
    }
    if (len > BAND_W) {                    // cold (only after exact fallback)
      for (int t = s + BAND_W; t < i; ++t) {
        a0 += dp[(size_t)t * NV4 + q0];
        a1 += dp[(size_t)t * NV4 + q1];
      }
    }
    const float inv = 1.0f / (float)len;
    a0.x *= inv; a0.y *= inv; a0.z *= inv; a0.w *= inv;
    a1.x *= inv; a1.y *= inv; a1.z *= inv; a1.w *= inv;
    mp[(size_t)(i - 1) * NV4 + q0] = a0;
    mp[(size_t)(i - 1) * NV4 + q1] = a1;
    if (lane == 0) fl[i - 1] = 1.0f;
  }
}

// --------------------------------------------------- fallback (R2, green)
__global__ __launch_bounds__(64, 1)
void dist_agg_mono(const float* __restrict__ data,
                   const float* __restrict__ thrp,
                   float* __restrict__ out, int B) {
  const int b    = blockIdx.x;
  const int lane = threadIdx.x;
  const float thr = thrp[0];
  const v4* __restrict__ dp = reinterpret_cast<const v4*>(data) + (size_t)b * T_F * NV4;
  v4* __restrict__ mp       = reinterpret_cast<v4*>(out) + (size_t)b * (T_F - 1) * NV4;
  float* __restrict__ fp    = out + (size_t)B * (T_F - 1) * D_DIM + (size_t)b * (T_F - 1);
  const int s0 = lane, s1 = 64 + lane;

  v4 rep0 = dp[s0], rep1 = dp[s1];
  v4 cs0  = rep0,  cs1  = rep1;
  v4 ss0  = {0.f,0.f,0.f,0.f}, ss1 = {0.f,0.f,0.f,0.f};
  int ind = 0, fi = 0;
  const float F0     = 1.9f / (1.0f + expf(-1.0f)) + 0.4f;
  const float tf0    = thr * F0;
  const float tf2_f0 = tf0 * tf0;
  float tf2 = tf2_f0;

  for (int i = 1; i < T_F; ++i) {
    float an      = fminf((float)fi, 80.0f);
    float Fn      = 1.9f / (1.0f + expf(an)) + 0.4f;
    float tn      = thr * Fn;
    float tf2_inc = tn * tn;
    v4 fa = dp[(size_t)i * NV4 + s0];
    v4 fb = dp[(size_t)i * NV4 + s1];
    v4 d0 = rep0 - fa, d1 = rep1 - fb;
    float part = d0.x*d0.x + d0.y*d0.y + d0.z*d0.z + d0.w*d0.w
               + d1.x*d1.x + d1.y*d1.y + d1.z*d1.z + d1.w*d1.w;
    float dist2 = wave_sum64(part);
    bool bnd = dist2 > tf2;
    float inv = 1.0f / (float)(i - ind);
    v4 df0 = cs0 - ss0, df1 = cs1 - ss1;
    v4 m0, m1, z = {0.f,0.f,0.f,0.f};
    m0.x = df0.x*inv; m0.y = df0.y*inv; m0.z = df0.z*inv; m0.w = df0.w*inv;
    m1.x = df1.x*inv; m1.y = df1.y*inv; m1.z = df1.z*inv; m1.w = df1.w*inv;
    mp[(size_t)(i-1) * NV4 + s0] = sel4(bnd, m0, z);
    mp[(size_t)(i-1) * NV4 + s1] = sel4(bnd, m1, z);
    if (lane == 0) fp[i-1] = bnd ? 1.0f : 0.0f;
    rep0 = sel4(bnd, fa, rep0); rep1 = sel4(bnd, fb, rep1);
    ss0  = sel4(bnd, cs0, ss0); ss1  = sel4(bnd, cs1, ss1);
    ind  = bnd ? i : ind;
    fi   = bnd ? 0 : fi + 1;
    tf2  = bnd ? tf2_f0 : tf2_inc;
    cs0 += fa; cs1 += fb;
  }
}

// ----------------------------------------------------------------- launch
extern "C" void kernel_launch(void* const* d_in, const int* in_sizes, int n_in,
                              void* d_out, int out_size, void* d_ws, size_t ws_size,
                              hipStream_t stream) {
  const float* data = (const float*)d_in[0];
  const float* thr  = (const float*)d_in[1];
  float* out        = (float*)d_out;
  const int B = in_sizes[0] / (T_F * D_DIM);

  const size_t need = (size_t)B * 1024 + (size_t)B * 1024 * 4;  // delta + so

  if (ws_size >= need) {
    unsigned char* deltab = (unsigned char*)d_ws;
    int* scan_out = (int*)((unsigned char*)d_ws + (size_t)B * 1024);
    const int runs = B * RPBB;
    band_kernel<<<(runs + 3) / 4, 256, 0, stream>>>(data, thr, deltab, B);
    scan_kernel<<<B, 64, 0, stream>>>(data, thr, deltab, scan_out, B);
    mean_kernel<<<dim3((T_F - 2) / 8 + 1, B), 256, 0, stream>>>(data, scan_out, out, B);
  } else {
    dist_agg_mono<<<B, 64, 0, stream>>>(data, thr, out, B);
  }
}

// Round 6
// 153.840 us; speedup vs baseline: 3.1287x; 1.0026x over previous
//
#include <hip/hip_runtime.h>
#include <math.h>

// DistanceAggregation v6.
// Identity: f_i == i-1-ind  =>  boundary test at step i with last boundary s is
//   dist^2(f_s, f_i) > (thr*F[i-1-s])^2   -- no carried threshold state.
// 1) band_kernel (W=4, ring-8, RUN=16): delta[s] = 1+first w<4 boundary
//    (0 = overflow sentinel -> exact fallback; keeps ANY data correct).
// 2) scan_kernel: chase delta[] (nibble-packed, 2 VGPRs/lane, ~1 readlane
//    hop per segment); so[i]=segment start at boundaries; exact cold fallback.
// 3) mean_kernel: one row/wave, wave-uniform-length segment mean loop.
// Fixed harness overhead in dur: ~82us of d_ws/d_out poison fills (measured
// R2: dur 481 - kernel 399).

typedef float v4 __attribute__((ext_vector_type(4)));

#define T_F    1000
#define D_DIM  512
#define NV4    128
#define BAND_W 4
#define RUNB   16           // rows per wave in band kernel
#define RPBB   63           // ceil(999/16)

__device__ __forceinline__ float wave_sum64(float x) {
  x += __shfl_xor(x, 1);
  x += __shfl_xor(x, 2);
  x += __shfl_xor(x, 4);
  x += __shfl_xor(x, 8);
  x += __shfl_xor(x, 16);
  x += __shfl_xor(x, 32);
  return x;
}

__device__ __forceinline__ v4 sel4(bool c, v4 a, v4 b) {
  v4 r;
  r.x = c ? a.x : b.x; r.y = c ? a.y : b.y;
  r.z = c ? a.z : b.z; r.w = c ? a.w : b.w;
  return r;
}

// 8 bytes (two u32, values 0..15) -> 8 packed nibbles
__device__ __forceinline__ unsigned pack8(unsigned x, unsigned y) {
  unsigned a = x & 0x0F0F0F0Fu; a |= a >> 4;
  unsigned p = (a & 0xFFu) | ((a >> 8) & 0xFF00u);
  unsigned b = y & 0x0F0F0F0Fu; b |= b >> 4;
  unsigned q = (b & 0xFFu) | ((b >> 8) & 0xFF00u);
  return p | (q << 16);
}

// ---------------------------------------------------------------- kernel 1
__global__ __launch_bounds__(256)
void band_kernel(const float* __restrict__ data, const float* __restrict__ thrp,
                 unsigned char* __restrict__ deltab, int B) {
  const int lane = threadIdx.x & 63;
  const int wid  = threadIdx.x >> 6;
  const int run  = blockIdx.x * 4 + wid;
  if (run >= B * RPBB) return;
  const int b   = run / RPBB;
  const int s0i = (run % RPBB) * RUNB;       // s0i % 8 == 0

  const v4* __restrict__ dp = reinterpret_cast<const v4*>(data) + (size_t)b * T_F * NV4;
  unsigned char* __restrict__ dbp = deltab + (size_t)b * 1024;

  // per-lane threshold^2 for w = lane&3:  F[w] = 1.9/(1+exp(w-1))+0.4
  const int   wl  = lane & 3;
  const float thr = thrp[0];
  float Ff  = 1.9f / (1.0f + expf((float)wl - 1.0f)) + 0.4f;
  float tt  = thr * Ff;
  const float tf2l = tt * tt;

  const int q0 = lane, q1 = 64 + lane;
  // ring: slot t&7 holds frame t; init frames s0i..s0i+7 (clamped)
  v4 ra[8], rb[8];
#pragma unroll
  for (int d = 0; d < 8; ++d) {
    int t = s0i + d; if (t > T_F - 1) t = T_F - 1;
    ra[d] = dp[(size_t)t * NV4 + q0];
    rb[d] = dp[(size_t)t * NV4 + q1];
  }

#pragma unroll
  for (int u = 0; u < RUNB; ++u) {
    const int s  = s0i + u;                  // segment start; slot = u&7
    const int su = u & 7;
    float p[BAND_W];
#pragma unroll
    for (int w = 0; w < BAND_W; ++w) {
      const int sj = (u + 1 + w) & 7;        // slot of frame s+1+w (compile-time)
      v4 d0 = ra[su] - ra[sj];
      v4 d1 = rb[su] - rb[sj];
      p[w] = d0.x*d0.x + d0.y*d0.y + d0.z*d0.z + d0.w*d0.w
           + d1.x*d1.x + d1.y*d1.y + d1.z*d1.z + d1.w*d1.w;
    }
    // prefetch frame s+8 (issued now, consumed 4+ rows later; frame s is dead
    // after this row, so its slot su is the landing spot)
    int tn = s + 8; if (tn > T_F - 1) tn = T_F - 1;
    v4 na = dp[(size_t)tn * NV4 + q0];
    v4 nb = dp[(size_t)tn * NV4 + q1];

#pragma unroll
    for (int w = 0; w < BAND_W; ++w) {
      p[w] += __shfl_xor(p[w], 1);
      p[w] += __shfl_xor(p[w], 2);
      p[w] += __shfl_xor(p[w], 4);
    }
    const bool bt0 = (lane & 1) != 0, bt1 = (lane & 2) != 0;
    float q0v  = bt0 ? p[1] : p[0];
    float q1v  = bt0 ? p[3] : p[2];
    float comb = bt1 ? q1v : q0v;
    comb += __shfl_xor(comb, 8);
    comb += __shfl_xor(comb, 16);
    comb += __shfl_xor(comb, 32);
    // lane L now holds full dist^2 for w = L&3
    bool valid = (s + 1 + wl) <= (T_F - 1);
    bool bnd   = valid && (comb > tf2l);
    unsigned long long m = __ballot(bnd);
    int delta = __ffsll((unsigned long long)(m & 0xFull));  // 1..4, 0 = none
    if (lane == 0 && s <= T_F - 2) dbp[s] = (unsigned char)delta;

    ra[su] = na; rb[su] = nb;                // commit prefetch after use of slot
  }
}

// ---------------------------------------------------------------- kernel 2
__global__ __launch_bounds__(64, 1)
void scan_kernel(const float* __restrict__ data, const float* __restrict__ thrp,
                 const unsigned char* __restrict__ deltab,
                 int* __restrict__ scan_out, int B) {
  const int b    = blockIdx.x;
  const int lane = threadIdx.x;
  const v4* __restrict__ dp = reinterpret_cast<const v4*>(data) + (size_t)b * T_F * NV4;
  int* __restrict__ so = scan_out + (size_t)b * 1024;

  // default: no boundary
#pragma unroll
  for (int j = 0; j < 16; ++j) so[j * 64 + lane] = -1;

  // pack 16 delta bytes per lane into 2 nibble words
  const uint4 dd = reinterpret_cast<const uint4*>(deltab + (size_t)b * 1024)[lane];
  unsigned plo = pack8(dd.x, dd.y);
  unsigned phi = pack8(dd.z, dd.w);

  __builtin_amdgcn_s_waitcnt(0);   // -1 stores drained before chase overwrites

  int s = 0;
  bool need_exact = false;
  while (s < T_F - 1) {
    unsigned lo = (unsigned)__builtin_amdgcn_readlane((int)plo, s >> 4);
    unsigned hi = (unsigned)__builtin_amdgcn_readlane((int)phi, s >> 4);
    unsigned word = (s & 8) ? hi : lo;
    int delta = (word >> ((s & 7) * 4)) & 15;
    if (delta == 0) { need_exact = (s < T_F - 1 - BAND_W); break; }
    s += delta;
    if (lane == 0) so[s] = s - delta;
  }

  if (need_exact) {   // cold: exact continuation from last boundary s
    const float thr = thrp[0];
    const int q0 = lane, q1 = 64 + lane;
    int ind = s, f = 0;
    v4 rep0 = dp[(size_t)ind * NV4 + q0];
    v4 rep1 = dp[(size_t)ind * NV4 + q1];
    for (int i = s + 1; i <= T_F - 1; ++i) {
      float av = fminf((float)f - 1.0f, 80.0f);
      float Ff = 1.9f / (1.0f + expf(av)) + 0.4f;
      float t2 = thr * Ff; t2 *= t2;
      v4 x0 = dp[(size_t)i * NV4 + q0];
      v4 x1 = dp[(size_t)i * NV4 + q1];
      v4 d0 = rep0 - x0, d1 = rep1 - x1;
      float part = d0.x*d0.x + d0.y*d0.y + d0.z*d0.z + d0.w*d0.w
                 + d1.x*d1.x + d1.y*d1.y + d1.z*d1.z + d1.w*d1.w;
      float d2 = wave_sum64(part);
      bool bnd = d2 > t2;
      if (bnd) {
        if (lane == 0) so[i] = ind;
        ind = i; f = 0; rep0 = x0; rep1 = x1;
      } else {
        f += 1;
      }
    }
  }
}

// ---------------------------------------------------------------- kernel 3
__global__ __launch_bounds__(256)
void mean_kernel(const float* __restrict__ data, const int* __restrict__ scan_out,
                 float* __restrict__ out, int B) {
  const int lane = threadIdx.x & 63;
  const int wid  = threadIdx.x >> 6;
  const int b    = blockIdx.y;
  const int i    = 1 + blockIdx.x * 4 + wid;   // one row per wave
  if (i > T_F - 1) return;

  const v4* __restrict__ dp  = reinterpret_cast<const v4*>(data) + (size_t)b * T_F * NV4;
  const int* __restrict__ so = scan_out + (size_t)b * 1024;
  v4* __restrict__ mp        = reinterpret_cast<v4*>(out) + (size_t)b * (T_F - 1) * NV4;
  float* __restrict__ fl     = out + (size_t)B * (T_F - 1) * D_DIM + (size_t)b * (T_F - 1);
  const int q0 = lane, q1 = 64 + lane;

  const int s = so[i];
  v4 z = {0.f, 0.f, 0.f, 0.f};
  if (s < 0) {
    mp[(size_t)(i - 1) * NV4 + q0] = z;
    mp[(size_t)(i - 1) * NV4 + q1] = z;
    if (lane == 0) fl[i - 1] = 0.0f;
    return;
  }
  const int len = i - s;                     // wave-uniform (s uniform per row)
  v4 a0 = z, a1 = z;
  for (int t = s; t < i; ++t) {              // uniform trip count, no masking
    a0 += dp[(size_t)t * NV4 + q0];
    a1 += dp[(size_t)t * NV4 + q1];
  }
  const float inv = 1.0f / (float)len;
  a0.x *= inv; a0.y *= inv; a0.z *= inv; a0.w *= inv;
  a1.x *= inv; a1.y *= inv; a1.z *= inv; a1.w *= inv;
  mp[(size_t)(i - 1) * NV4 + q0] = a0;
  mp[(size_t)(i - 1) * NV4 + q1] = a1;
  if (lane == 0) fl[i - 1] = 1.0f;
}

// --------------------------------------------------- fallback (R2, green)
__global__ __launch_bounds__(64, 1)
void dist_agg_mono(const float* __restrict__ data,
                   const float* __restrict__ thrp,
                   float* __restrict__ out, int B) {
  const int b    = blockIdx.x;
  const int lane = threadIdx.x;
  const float thr = thrp[0];
  const v4* __restrict__ dp = reinterpret_cast<const v4*>(data) + (size_t)b * T_F * NV4;
  v4* __restrict__ mp       = reinterpret_cast<v4*>(out) + (size_t)b * (T_F - 1) * NV4;
  float* __restrict__ fp    = out + (size_t)B * (T_F - 1) * D_DIM + (size_t)b * (T_F - 1);
  const int s0 = lane, s1 = 64 + lane;

  v4 rep0 = dp[s0], rep1 = dp[s1];
  v4 cs0  = rep0,  cs1  = rep1;
  v4 ss0  = {0.f,0.f,0.f,0.f}, ss1 = {0.f,0.f,0.f,0.f};
  int ind = 0, fi = 0;
  const float F0     = 1.9f / (1.0f + expf(-1.0f)) + 0.4f;
  const float tf0    = thr * F0;
  const float tf2_f0 = tf0 * tf0;
  float tf2 = tf2_f0;

  for (int i = 1; i < T_F; ++i) {
    float an      = fminf((float)fi, 80.0f);
    float Fn      = 1.9f / (1.0f + expf(an)) + 0.4f;
    float tn      = thr * Fn;
    float tf2_inc = tn * tn;
    v4 fa = dp[(size_t)i * NV4 + s0];
    v4 fb = dp[(size_t)i * NV4 + s1];
    v4 d0 = rep0 - fa, d1 = rep1 - fb;
    float part = d0.x*d0.x + d0.y*d0.y + d0.z*d0.z + d0.w*d0.w
               + d1.x*d1.x + d1.y*d1.y + d1.z*d1.z + d1.w*d1.w;
    float dist2 = wave_sum64(part);
    bool bnd = dist2 > tf2;
    float inv = 1.0f / (float)(i - ind);
    v4 df0 = cs0 - ss0, df1 = cs1 - ss1;
    v4 m0, m1, z = {0.f,0.f,0.f,0.f};
    m0.x = df0.x*inv; m0.y = df0.y*inv; m0.z = df0.z*inv; m0.w = df0.w*inv;
    m1.x = df1.x*inv; m1.y = df1.y*inv; m1.z = df1.z*inv; m1.w = df1.w*inv;
    mp[(size_t)(i-1) * NV4 + s0] = sel4(bnd, m0, z);
    mp[(size_t)(i-1) * NV4 + s1] = sel4(bnd, m1, z);
    if (lane == 0) fp[i-1] = bnd ? 1.0f : 0.0f;
    rep0 = sel4(bnd, fa, rep0); rep1 = sel4(bnd, fb, rep1);
    ss0  = sel4(bnd, cs0, ss0); ss1  = sel4(bnd, cs1, ss1);
    ind  = bnd ? i : ind;
    fi   = bnd ? 0 : fi + 1;
    tf2  = bnd ? tf2_f0 : tf2_inc;
    cs0 += fa; cs1 += fb;
  }
}

// ----------------------------------------------------------------- launch
extern "C" void kernel_launch(void* const* d_in, const int* in_sizes, int n_in,
                              void* d_out, int out_size, void* d_ws, size_t ws_size,
                              hipStream_t stream) {
  const float* data = (const float*)d_in[0];
  const float* thr  = (const float*)d_in[1];
  float* out        = (float*)d_out;
  const int B = in_sizes[0] / (T_F * D_DIM);

  const size_t need = (size_t)B * 1024 + (size_t)B * 1024 * 4;  // delta + so

  if (ws_size >= need) {
    unsigned char* deltab = (unsigned char*)d_ws;
    int* scan_out = (int*)((unsigned char*)d_ws + (size_t)B * 1024);
    const int runs = B * RPBB;
    band_kernel<<<(runs + 3) / 4, 256, 0, stream>>>(data, thr, deltab, B);
    scan_kernel<<<B, 64, 0, stream>>>(data, thr, deltab, scan_out, B);
    mean_kernel<<<dim3((T_F - 2) / 4 + 1, B), 256, 0, stream>>>(data, scan_out, out, B);
  } else {
    dist_agg_mono<<<B, 64, 0, stream>>>(data, thr, out, B);
  }
}

// Round 7
// 153.477 us; speedup vs baseline: 3.1361x; 1.0024x over previous
//
#include <hip/hip_runtime.h>
#include <math.h>

// DistanceAggregation v7.
// Identity: f_i == i-1-ind  =>  boundary test at step i with last boundary s is
//   dist^2(f_s, f_i) > (thr*F[i-1-s])^2   -- no carried threshold state.
// 1) band_kernel (W=4, ring-8, RUN=16): delta[s] = 1+first w<4 boundary
//    (0 = overflow sentinel -> exact fallback; keeps ANY data correct).
// 2) scan_kernel: chase delta[] (nibble-packed, 2 VGPRs/lane, ~1 readlane
//    hop per segment); so[i]=segment start at boundaries; exact cold fallback.
// 3) mean_kernel v3: 4 rows/wave, one int4 so-load per wave (all gather
//    addresses known upfront -> ~32 loads in flight), branch-free masked-4
//    hot path, nontemporal output stores.
// Fixed harness overhead in dur: ~82us of d_ws/d_out poison fills + d_in
// restore (measured R2: dur 481 - kernel 399).

typedef float v4 __attribute__((ext_vector_type(4)));

#define T_F    1000
#define D_DIM  512
#define NV4    128
#define BAND_W 4
#define RUNB   16           // rows per wave in band kernel
#define RPBB   63           // ceil(999/16)

__device__ __forceinline__ float wave_sum64(float x) {
  x += __shfl_xor(x, 1);
  x += __shfl_xor(x, 2);
  x += __shfl_xor(x, 4);
  x += __shfl_xor(x, 8);
  x += __shfl_xor(x, 16);
  x += __shfl_xor(x, 32);
  return x;
}

__device__ __forceinline__ v4 sel4(bool c, v4 a, v4 b) {
  v4 r;
  r.x = c ? a.x : b.x; r.y = c ? a.y : b.y;
  r.z = c ? a.z : b.z; r.w = c ? a.w : b.w;
  return r;
}

// 8 bytes (two u32, values 0..15) -> 8 packed nibbles
__device__ __forceinline__ unsigned pack8(unsigned x, unsigned y) {
  unsigned a = x & 0x0F0F0F0Fu; a |= a >> 4;
  unsigned p = (a & 0xFFu) | ((a >> 8) & 0xFF00u);
  unsigned b = y & 0x0F0F0F0Fu; b |= b >> 4;
  unsigned q = (b & 0xFFu) | ((b >> 8) & 0xFF00u);
  return p | (q << 16);
}

// ---------------------------------------------------------------- kernel 1
__global__ __launch_bounds__(256)
void band_kernel(const float* __restrict__ data, const float* __restrict__ thrp,
                 unsigned char* __restrict__ deltab, int B) {
  const int lane = threadIdx.x & 63;
  const int wid  = threadIdx.x >> 6;
  const int run  = blockIdx.x * 4 + wid;
  if (run >= B * RPBB) return;
  const int b   = run / RPBB;
  const int s0i = (run % RPBB) * RUNB;       // s0i % 8 == 0

  const v4* __restrict__ dp = reinterpret_cast<const v4*>(data) + (size_t)b * T_F * NV4;
  unsigned char* __restrict__ dbp = deltab + (size_t)b * 1024;

  // per-lane threshold^2 for w = lane&3:  F[w] = 1.9/(1+exp(w-1))+0.4
  const int   wl  = lane & 3;
  const float thr = thrp[0];
  float Ff  = 1.9f / (1.0f + expf((float)wl - 1.0f)) + 0.4f;
  float tt  = thr * Ff;
  const float tf2l = tt * tt;

  const int q0 = lane, q1 = 64 + lane;
  // ring: slot t&7 holds frame t; init frames s0i..s0i+7 (clamped)
  v4 ra[8], rb[8];
#pragma unroll
  for (int d = 0; d < 8; ++d) {
    int t = s0i + d; if (t > T_F - 1) t = T_F - 1;
    ra[d] = dp[(size_t)t * NV4 + q0];
    rb[d] = dp[(size_t)t * NV4 + q1];
  }

#pragma unroll
  for (int u = 0; u < RUNB; ++u) {
    const int s  = s0i + u;                  // segment start; slot = u&7
    const int su = u & 7;
    float p[BAND_W];
#pragma unroll
    for (int w = 0; w < BAND_W; ++w) {
      const int sj = (u + 1 + w) & 7;        // slot of frame s+1+w (compile-time)
      v4 d0 = ra[su] - ra[sj];
      v4 d1 = rb[su] - rb[sj];
      p[w] = d0.x*d0.x + d0.y*d0.y + d0.z*d0.z + d0.w*d0.w
           + d1.x*d1.x + d1.y*d1.y + d1.z*d1.z + d1.w*d1.w;
    }
    // prefetch frame s+8 (issued now, consumed 4+ rows later; frame s is dead
    // after this row, so its slot su is the landing spot)
    int tn = s + 8; if (tn > T_F - 1) tn = T_F - 1;
    v4 na = dp[(size_t)tn * NV4 + q0];
    v4 nb = dp[(size_t)tn * NV4 + q1];

#pragma unroll
    for (int w = 0; w < BAND_W; ++w) {
      p[w] += __shfl_xor(p[w], 1);
      p[w] += __shfl_xor(p[w], 2);
      p[w] += __shfl_xor(p[w], 4);
    }
    const bool bt0 = (lane & 1) != 0, bt1 = (lane & 2) != 0;
    float q0v  = bt0 ? p[1] : p[0];
    float q1v  = bt0 ? p[3] : p[2];
    float comb = bt1 ? q1v : q0v;
    comb += __shfl_xor(comb, 8);
    comb += __shfl_xor(comb, 16);
    comb += __shfl_xor(comb, 32);
    // lane L now holds full dist^2 for w = L&3
    bool valid = (s + 1 + wl) <= (T_F - 1);
    bool bnd   = valid && (comb > tf2l);
    unsigned long long m = __ballot(bnd);
    int delta = __ffsll((unsigned long long)(m & 0xFull));  // 1..4, 0 = none
    if (lane == 0 && s <= T_F - 2) dbp[s] = (unsigned char)delta;

    ra[su] = na; rb[su] = nb;                // commit prefetch after use of slot
  }
}

// ---------------------------------------------------------------- kernel 2
__global__ __launch_bounds__(64, 1)
void scan_kernel(const float* __restrict__ data, const float* __restrict__ thrp,
                 const unsigned char* __restrict__ deltab,
                 int* __restrict__ scan_out, int B) {
  const int b    = blockIdx.x;
  const int lane = threadIdx.x;
  const v4* __restrict__ dp = reinterpret_cast<const v4*>(data) + (size_t)b * T_F * NV4;
  int* __restrict__ so = scan_out + (size_t)b * 1024;

  // default: no boundary
#pragma unroll
  for (int j = 0; j < 16; ++j) so[j * 64 + lane] = -1;

  // pack 16 delta bytes per lane into 2 nibble words
  const uint4 dd = reinterpret_cast<const uint4*>(deltab + (size_t)b * 1024)[lane];
  unsigned plo = pack8(dd.x, dd.y);
  unsigned phi = pack8(dd.z, dd.w);

  __builtin_amdgcn_s_waitcnt(0);   // -1 stores drained before chase overwrites

  int s = 0;
  bool need_exact = false;
  while (s < T_F - 1) {
    unsigned lo = (unsigned)__builtin_amdgcn_readlane((int)plo, s >> 4);
    unsigned hi = (unsigned)__builtin_amdgcn_readlane((int)phi, s >> 4);
    unsigned word = (s & 8) ? hi : lo;
    int delta = (word >> ((s & 7) * 4)) & 15;
    if (delta == 0) { need_exact = (s < T_F - 1 - BAND_W); break; }
    s += delta;
    if (lane == 0) so[s] = s - delta;
  }

  if (need_exact) {   // cold: exact continuation from last boundary s
    const float thr = thrp[0];
    const int q0 = lane, q1 = 64 + lane;
    int ind = s, f = 0;
    v4 rep0 = dp[(size_t)ind * NV4 + q0];
    v4 rep1 = dp[(size_t)ind * NV4 + q1];
    for (int i = s + 1; i <= T_F - 1; ++i) {
      float av = fminf((float)f - 1.0f, 80.0f);
      float Ff = 1.9f / (1.0f + expf(av)) + 0.4f;
      float t2 = thr * Ff; t2 *= t2;
      v4 x0 = dp[(size_t)i * NV4 + q0];
      v4 x1 = dp[(size_t)i * NV4 + q1];
      v4 d0 = rep0 - x0, d1 = rep1 - x1;
      float part = d0.x*d0.x + d0.y*d0.y + d0.z*d0.z + d0.w*d0.w
                 + d1.x*d1.x + d1.y*d1.y + d1.z*d1.z + d1.w*d1.w;
      float d2 = wave_sum64(part);
      bool bnd = d2 > t2;
      if (bnd) {
        if (lane == 0) so[i] = ind;
        ind = i; f = 0; rep0 = x0; rep1 = x1;
      } else {
        f += 1;
      }
    }
  }
}

// ---------------------------------------------------------------- kernel 3
// 4 rows per wave; one int4 so-load gives all gather addresses upfront.
__global__ __launch_bounds__(256)
void mean_kernel(const float* __restrict__ data, const int* __restrict__ scan_out,
                 float* __restrict__ out, int B) {
  const int lane = threadIdx.x & 63;
  const int wv   = threadIdx.x >> 6;
  const int b    = blockIdx.y;
  const int i0   = blockIdx.x * 16 + wv * 4;     // rows i0..i0+3 (row 0 skipped)

  const v4* __restrict__ dp  = reinterpret_cast<const v4*>(data) + (size_t)b * T_F * NV4;
  const int* __restrict__ so = scan_out + (size_t)b * 1024;
  v4* __restrict__ mp        = reinterpret_cast<v4*>(out) + (size_t)b * (T_F - 1) * NV4;
  float* __restrict__ fl     = out + (size_t)B * (T_F - 1) * D_DIM + (size_t)b * (T_F - 1);
  const int q0 = lane, q1 = 64 + lane;

  // all 4 segment starts in one aligned 16B load (so[] is 1024-padded, all
  // entries initialized by scan_kernel)
  const int4 sv = *reinterpret_cast<const int4*>(so + i0);
  const int sarr[4] = {sv.x, sv.y, sv.z, sv.w};

  const v4 z = {0.f, 0.f, 0.f, 0.f};
#pragma unroll
  for (int q = 0; q < 4; ++q) {
    const int i = i0 + q;
    if (i < 1 || i > T_F - 1) continue;
    const int s = sarr[q];
    if (s < 0) {
      __builtin_nontemporal_store(z, &mp[(size_t)(i - 1) * NV4 + q0]);
      __builtin_nontemporal_store(z, &mp[(size_t)(i - 1) * NV4 + q1]);
      if (lane == 0) __builtin_nontemporal_store(0.0f, &fl[i - 1]);
      continue;
    }
    const int len = i - s;                    // wave-uniform
    v4 a0 = z, a1 = z;
    if (len <= BAND_W) {                      // hot: branch-free masked gather
#pragma unroll
      for (int j = 0; j < BAND_W; ++j) {
        const int t = (j < len) ? (s + j) : (i - 1);   // clamped, in-segment
        const float msk = (j < len) ? 1.0f : 0.0f;
        v4 x0 = dp[(size_t)t * NV4 + q0];
        v4 x1 = dp[(size_t)t * NV4 + q1];
        a0.x += x0.x * msk; a0.y += x0.y * msk; a0.z += x0.z * msk; a0.w += x0.w * msk;
        a1.x += x1.x * msk; a1.y += x1.y * msk; a1.z += x1.z * msk; a1.w += x1.w * msk;
      }
    } else {                                  // cold: post-fallback long segment
      for (int t = s; t < i; ++t) {
        a0 += dp[(size_t)t * NV4 + q0];
        a1 += dp[(size_t)t * NV4 + q1];
      }
    }
    const float inv = 1.0f / (float)len;
    a0.x *= inv; a0.y *= inv; a0.z *= inv; a0.w *= inv;
    a1.x *= inv; a1.y *= inv; a1.z *= inv; a1.w *= inv;
    __builtin_nontemporal_store(a0, &mp[(size_t)(i - 1) * NV4 + q0]);
    __builtin_nontemporal_store(a1, &mp[(size_t)(i - 1) * NV4 + q1]);
    if (lane == 0) __builtin_nontemporal_store(1.0f, &fl[i - 1]);
  }
}

// --------------------------------------------------- fallback (R2, green)
__global__ __launch_bounds__(64, 1)
void dist_agg_mono(const float* __restrict__ data,
                   const float* __restrict__ thrp,
                   float* __restrict__ out, int B) {
  const int b    = blockIdx.x;
  const int lane = threadIdx.x;
  const float thr = thrp[0];
  const v4* __restrict__ dp = reinterpret_cast<const v4*>(data) + (size_t)b * T_F * NV4;
  v4* __restrict__ mp       = reinterpret_cast<v4*>(out) + (size_t)b * (T_F - 1) * NV4;
  float* __restrict__ fp    = out + (size_t)B * (T_F - 1) * D_DIM + (size_t)b * (T_F - 1);
  const int s0 = lane, s1 = 64 + lane;

  v4 rep0 = dp[s0], rep1 = dp[s1];
  v4 cs0  = rep0,  cs1  = rep1;
  v4 ss0  = {0.f,0.f,0.f,0.f}, ss1 = {0.f,0.f,0.f,0.f};
  int ind = 0, fi = 0;
  const float F0     = 1.9f / (1.0f + expf(-1.0f)) + 0.4f;
  const float tf0    = thr * F0;
  const float tf2_f0 = tf0 * tf0;
  float tf2 = tf2_f0;

  for (int i = 1; i < T_F; ++i) {
    float an      = fminf((float)fi, 80.0f);
    float Fn      = 1.9f / (1.0f + expf(an)) + 0.4f;
    float tn      = thr * Fn;
    float tf2_inc = tn * tn;
    v4 fa = dp[(size_t)i * NV4 + s0];
    v4 fb = dp[(size_t)i * NV4 + s1];
    v4 d0 = rep0 - fa, d1 = rep1 - fb;
    float part = d0.x*d0.x + d0.y*d0.y + d0.z*d0.z + d0.w*d0.w
               + d1.x*d1.x + d1.y*d1.y + d1.z*d1.z + d1.w*d1.w;
    float dist2 = wave_sum64(part);
    bool bnd = dist2 > tf2;
    float inv = 1.0f / (float)(i - ind);
    v4 df0 = cs0 - ss0, df1 = cs1 - ss1;
    v4 m0, m1, z = {0.f,0.f,0.f,0.f};
    m0.x = df0.x*inv; m0.y = df0.y*inv; m0.z = df0.z*inv; m0.w = df0.w*inv;
    m1.x = df1.x*inv; m1.y = df1.y*inv; m1.z = df1.z*inv; m1.w = df1.w*inv;
    mp[(size_t)(i-1) * NV4 + s0] = sel4(bnd, m0, z);
    mp[(size_t)(i-1) * NV4 + s1] = sel4(bnd, m1, z);
    if (lane == 0) fp[i-1] = bnd ? 1.0f : 0.0f;
    rep0 = sel4(bnd, fa, rep0); rep1 = sel4(bnd, fb, rep1);
    ss0  = sel4(bnd, cs0, ss0); ss1  = sel4(bnd, cs1, ss1);
    ind  = bnd ? i : ind;
    fi   = bnd ? 0 : fi + 1;
    tf2  = bnd ? tf2_f0 : tf2_inc;
    cs0 += fa; cs1 += fb;
  }
}

// ----------------------------------------------------------------- launch
extern "C" void kernel_launch(void* const* d_in, const int* in_sizes, int n_in,
                              void* d_out, int out_size, void* d_ws, size_t ws_size,
                              hipStream_t stream) {
  const float* data = (const float*)d_in[0];
  const float* thr  = (const float*)d_in[1];
  float* out        = (float*)d_out;
  const int B = in_sizes[0] / (T_F * D_DIM);

  const size_t need = (size_t)B * 1024 + (size_t)B * 1024 * 4;  // delta + so

  if (ws_size >= need) {
    unsigned char* deltab = (unsigned char*)d_ws;
    int* scan_out = (int*)((unsigned char*)d_ws + (size_t)B * 1024);
    const int runs = B * RPBB;
    band_kernel<<<(runs + 3) / 4, 256, 0, stream>>>(data, thr, deltab, B);
    scan_kernel<<<B, 64, 0, stream>>>(data, thr, deltab, scan_out, B);
    mean_kernel<<<dim3(63, B), 256, 0, stream>>>(data, scan_out, out, B);
  } else {
    dist_agg_mono<<<B, 64, 0, stream>>>(data, thr, out, B);
  }
}